// Round 1
// baseline (34.020 us; speedup 1.0000x reference)
//
#include <hip/hip_runtime.h>

#define ETA 0.5f
#define NBLOCKS 2048
#define NTHREADS 256

__device__ __forceinline__ float wave_reduce_sum(float v) {
#pragma unroll
    for (int off = 32; off > 0; off >>= 1)
        v += __shfl_down(v, off, 64);
    return v;
}

__global__ __launch_bounds__(NTHREADS) void pnu_partial_kernel(
    const float* __restrict__ y, const int* __restrict__ t,
    float* __restrict__ partials, int n, int nblocks) {
    const int nvec = n >> 2;
    const float4* __restrict__ y4 = reinterpret_cast<const float4*>(y);
    const int4* __restrict__ t4 = reinterpret_cast<const int4*>(t);

    float sPp = 0.f, sPm = 0.f, sNm = 0.f, sUm = 0.f;
    float cP = 0.f, cN = 0.f, cU = 0.f;

    const int stride = gridDim.x * blockDim.x;
    for (int i = blockIdx.x * blockDim.x + threadIdx.x; i < nvec; i += stride) {
        float4 yv = y4[i];
        int4 tv = t4[i];
        float ys[4] = {yv.x, yv.y, yv.z, yv.w};
        int   ts[4] = {tv.x, tv.y, tv.z, tv.w};
#pragma unroll
        for (int j = 0; j < 4; ++j) {
            float s = __builtin_amdgcn_rcpf(1.0f + __expf(-ys[j]));  // sigmoid(y)
            int tt = ts[j];
            float isP = (tt == 1)  ? 1.0f : 0.0f;
            float isN = (tt == -1) ? 1.0f : 0.0f;
            float isU = (tt == 0)  ? 1.0f : 0.0f;
            sPp += isP * (1.0f - s);   // idx_p * sigmoid(-y)
            sPm += isP * s;            // idx_p * sigmoid(y)
            sNm += isN * s;            // idx_n * sigmoid(y)
            sUm += isU * s;            // idx_u * sigmoid(y)
            cP += isP; cN += isN; cU += isU;
        }
    }

    // scalar tail (n not a multiple of 4) — handled by one thread
    if (blockIdx.x == 0 && threadIdx.x == 0) {
        for (int i = (nvec << 2); i < n; ++i) {
            float s = __builtin_amdgcn_rcpf(1.0f + __expf(-y[i]));
            int tt = t[i];
            float isP = (tt == 1)  ? 1.0f : 0.0f;
            float isN = (tt == -1) ? 1.0f : 0.0f;
            float isU = (tt == 0)  ? 1.0f : 0.0f;
            sPp += isP * (1.0f - s);
            sPm += isP * s;
            sNm += isN * s;
            sUm += isU * s;
            cP += isP; cN += isN; cU += isU;
        }
    }

    // block reduction: wave shuffle -> LDS -> 7 outputs (SoA across blocks)
    float vals[7] = {sPp, sPm, sNm, sUm, cP, cN, cU};
    __shared__ float red[NTHREADS / 64][7];
    const int lane = threadIdx.x & 63;
    const int wave = threadIdx.x >> 6;
#pragma unroll
    for (int k = 0; k < 7; ++k) {
        float r = wave_reduce_sum(vals[k]);
        if (lane == 0) red[wave][k] = r;
    }
    __syncthreads();
    if (threadIdx.x < 7) {
        float r = 0.f;
#pragma unroll
        for (int w = 0; w < NTHREADS / 64; ++w) r += red[w][threadIdx.x];
        partials[threadIdx.x * nblocks + blockIdx.x] = r;
    }
}

__global__ __launch_bounds__(NTHREADS) void pnu_final_kernel(
    const float* __restrict__ partials, const float* __restrict__ p_ratio,
    float* __restrict__ out, int nblocks) {
    float acc[7] = {0.f, 0.f, 0.f, 0.f, 0.f, 0.f, 0.f};
    for (int i = threadIdx.x; i < nblocks; i += blockDim.x) {
#pragma unroll
        for (int k = 0; k < 7; ++k) acc[k] += partials[k * nblocks + i];
    }
    __shared__ float red[NTHREADS / 64][7];
    const int lane = threadIdx.x & 63;
    const int wave = threadIdx.x >> 6;
#pragma unroll
    for (int k = 0; k < 7; ++k) {
        float r = wave_reduce_sum(acc[k]);
        if (lane == 0) red[wave][k] = r;
    }
    __syncthreads();
    if (threadIdx.x == 0) {
        float tot[7];
#pragma unroll
        for (int k = 0; k < 7; ++k) {
            float r = 0.f;
#pragma unroll
            for (int w = 0; w < NTHREADS / 64; ++w) r += red[w][k];
            tot[k] = r;
        }
        const float sPp = tot[0], sPm = tot[1], sNm = tot[2], sUm = tot[3];
        const float nP = fmaxf(1.0f, tot[4]);
        const float nN = fmaxf(1.0f, tot[5]);
        const float nU = fmaxf(1.0f, tot[6]);

        const float R_P_plus  = sPp / nP;
        const float R_P_minus = sPm / nP;
        const float R_N_minus = sNm / nN;
        const float R_U_minus = sUm / nU;

        const float pi0 = p_ratio[0], pi1 = p_ratio[1];
        const float R_PN = pi0 * R_P_plus + pi1 * R_N_minus;
        const float R_PU = pi0 * (R_P_plus - R_P_minus) + R_U_minus;

        out[0] = (1.0f - ETA) * R_PN + ETA * R_PU;
    }
}

extern "C" void kernel_launch(void* const* d_in, const int* in_sizes, int n_in,
                              void* d_out, int out_size, void* d_ws, size_t ws_size,
                              hipStream_t stream) {
    const float* y = (const float*)d_in[0];
    const int* t = (const int*)d_in[1];
    const float* p_ratio = (const float*)d_in[2];
    float* out = (float*)d_out;
    float* partials = (float*)d_ws;

    const int n = in_sizes[0];
    int nblocks = NBLOCKS;
    // safety: each block writes 7 floats (SoA, stride = nblocks)
    size_t need = (size_t)nblocks * 7 * sizeof(float);
    while (need > ws_size && nblocks > 64) { nblocks >>= 1; need = (size_t)nblocks * 7 * sizeof(float); }

    pnu_partial_kernel<<<nblocks, NTHREADS, 0, stream>>>(y, t, partials, n, nblocks);
    pnu_final_kernel<<<1, NTHREADS, 0, stream>>>(partials, p_ratio, out, nblocks);
}

// Round 2
// 30.426 us; speedup vs baseline: 1.1182x; 1.1182x over previous
//
#include <hip/hip_runtime.h>

#define ETA 0.5f
#define NTHREADS 256
#define UNROLL 4
#define CHUNK (NTHREADS * UNROLL)   // float4 elements per block-chunk
#define NACC 5

__device__ __forceinline__ float wave_reduce_sum(float v) {
#pragma unroll
    for (int off = 32; off > 0; off >>= 1)
        v += __shfl_down(v, off, 64);
    return v;
}

// accumulators: sAll=Σs, sT=Σt*s, sA=Σ|t|*s, cT=Σt, cA=Σ|t|   (t ∈ {-1,0,1})
__device__ __forceinline__ void pnu_accum(float yy, int tt,
                                          float& sAll, float& sT, float& sA,
                                          float& cT, float& cA) {
    float s = __builtin_amdgcn_rcpf(1.0f + __expf(-yy));  // sigmoid(y)
    float tf = (float)tt;
    float ta = fabsf(tf);
    sAll += s;
    sT = fmaf(tf, s, sT);
    sA = fmaf(ta, s, sA);
    cT += tf;
    cA += ta;
}

__global__ __launch_bounds__(NTHREADS) void pnu_partial_kernel(
    const float* __restrict__ y, const int* __restrict__ t,
    float* __restrict__ partials, int n, int nblocks, int nfull) {
    const int nvec = n >> 2;
    const float4* __restrict__ y4 = reinterpret_cast<const float4*>(y);
    const int4* __restrict__ t4 = reinterpret_cast<const int4*>(t);

    float sAll = 0.f, sT = 0.f, sA = 0.f, cT = 0.f, cA = 0.f;

    // full chunks: no bounds checks, 8 independent 16B loads issued back-to-back
    for (int c = blockIdx.x; c < nfull; c += gridDim.x) {
        const int base = c * CHUNK + threadIdx.x;
        float4 yv[UNROLL];
        int4 tv[UNROLL];
#pragma unroll
        for (int u = 0; u < UNROLL; ++u) yv[u] = y4[base + u * NTHREADS];
#pragma unroll
        for (int u = 0; u < UNROLL; ++u) tv[u] = t4[base + u * NTHREADS];
#pragma unroll
        for (int u = 0; u < UNROLL; ++u) {
            pnu_accum(yv[u].x, tv[u].x, sAll, sT, sA, cT, cA);
            pnu_accum(yv[u].y, tv[u].y, sAll, sT, sA, cT, cA);
            pnu_accum(yv[u].z, tv[u].z, sAll, sT, sA, cT, cA);
            pnu_accum(yv[u].w, tv[u].w, sAll, sT, sA, cT, cA);
        }
    }

    // remainder (vec + scalar), handled by the last block only
    if (blockIdx.x == gridDim.x - 1) {
        for (int i = nfull * CHUNK + threadIdx.x; i < nvec; i += NTHREADS) {
            float4 yv = y4[i];
            int4 tv = t4[i];
            pnu_accum(yv.x, tv.x, sAll, sT, sA, cT, cA);
            pnu_accum(yv.y, tv.y, sAll, sT, sA, cT, cA);
            pnu_accum(yv.z, tv.z, sAll, sT, sA, cT, cA);
            pnu_accum(yv.w, tv.w, sAll, sT, sA, cT, cA);
        }
        for (int i = (nvec << 2) + threadIdx.x; i < n; i += NTHREADS)
            pnu_accum(y[i], t[i], sAll, sT, sA, cT, cA);
    }

    // block reduction: wave shuffle -> LDS -> 5 outputs (SoA across blocks)
    float vals[NACC] = {sAll, sT, sA, cT, cA};
    __shared__ float red[NTHREADS / 64][NACC];
    const int lane = threadIdx.x & 63;
    const int wave = threadIdx.x >> 6;
#pragma unroll
    for (int k = 0; k < NACC; ++k) {
        float r = wave_reduce_sum(vals[k]);
        if (lane == 0) red[wave][k] = r;
    }
    __syncthreads();
    if (threadIdx.x < NACC) {
        float r = 0.f;
#pragma unroll
        for (int w = 0; w < NTHREADS / 64; ++w) r += red[w][threadIdx.x];
        partials[threadIdx.x * nblocks + blockIdx.x] = r;
    }
}

#define FTHREADS 1024

__global__ __launch_bounds__(FTHREADS) void pnu_final_kernel(
    const float* __restrict__ partials, const float* __restrict__ p_ratio,
    float* __restrict__ out, int nblocks, int n) {
    float acc[NACC] = {0.f, 0.f, 0.f, 0.f, 0.f};
    for (int i = threadIdx.x; i < nblocks; i += FTHREADS) {
#pragma unroll
        for (int k = 0; k < NACC; ++k) acc[k] += partials[k * nblocks + i];
    }
    __shared__ float red[FTHREADS / 64][NACC];
    const int lane = threadIdx.x & 63;
    const int wave = threadIdx.x >> 6;
#pragma unroll
    for (int k = 0; k < NACC; ++k) {
        float r = wave_reduce_sum(acc[k]);
        if (lane == 0) red[wave][k] = r;
    }
    __syncthreads();
    if (threadIdx.x == 0) {
        float tot[NACC];
#pragma unroll
        for (int k = 0; k < NACC; ++k) {
            float r = 0.f;
#pragma unroll
            for (int w = 0; w < FTHREADS / 64; ++w) r += red[w][k];
            tot[k] = r;
        }
        const float sAll = tot[0], sT = tot[1], sA = tot[2];
        const float cT = tot[3], cA = tot[4];

        const float cP = 0.5f * (cA + cT);
        const float cN = 0.5f * (cA - cT);
        const float cU = (float)n - cA;
        const float sPm = 0.5f * (sA + sT);   // Σ idx_p * sigmoid(y)
        const float sNm = 0.5f * (sA - sT);   // Σ idx_n * sigmoid(y)
        const float sUm = sAll - sA;          // Σ idx_u * sigmoid(y)
        const float sPp = cP - sPm;           // Σ idx_p * sigmoid(-y)

        const float nP = fmaxf(1.0f, cP);
        const float nN = fmaxf(1.0f, cN);
        const float nU = fmaxf(1.0f, cU);

        const float R_P_plus  = sPp / nP;
        const float R_P_minus = sPm / nP;
        const float R_N_minus = sNm / nN;
        const float R_U_minus = sUm / nU;

        const float pi0 = p_ratio[0], pi1 = p_ratio[1];
        const float R_PN = pi0 * R_P_plus + pi1 * R_N_minus;
        const float R_PU = pi0 * (R_P_plus - R_P_minus) + R_U_minus;

        out[0] = (1.0f - ETA) * R_PN + ETA * R_PU;
    }
}

extern "C" void kernel_launch(void* const* d_in, const int* in_sizes, int n_in,
                              void* d_out, int out_size, void* d_ws, size_t ws_size,
                              hipStream_t stream) {
    const float* y = (const float*)d_in[0];
    const int* t = (const int*)d_in[1];
    const float* p_ratio = (const float*)d_in[2];
    float* out = (float*)d_out;
    float* partials = (float*)d_ws;

    const int n = in_sizes[0];
    const int nvec = n >> 2;
    const int nfull = nvec / CHUNK;
    const bool tail = (nfull * CHUNK * 4) < n;
    int nblocks = nfull + (tail ? 1 : 0);
    if (nblocks < 1) nblocks = 1;

    // cap grid to workspace capacity (chunk-stride loop covers the rest)
    int maxblocks = (int)(ws_size / (NACC * sizeof(float)));
    if (maxblocks < 1) maxblocks = 1;
    if (nblocks > maxblocks) nblocks = maxblocks;

    pnu_partial_kernel<<<nblocks, NTHREADS, 0, stream>>>(y, t, partials, n, nblocks, nfull);
    pnu_final_kernel<<<1, FTHREADS, 0, stream>>>(partials, p_ratio, out, nblocks, n);
}